// Round 8
// baseline (1297.050 us; speedup 1.0000x reference)
//
#include <hip/hip_runtime.h>
#include <math.h>

#define NTOK 16384
#define KDIM 2048
#define NEXP 64
#define NW   8                  // waves per block
#define BLOCK (NW * 64)         // 512 threads
#define ROWS 32                 // rows per block
#define KC   128                // k per staged chunk
#define NCH  (KDIM / KC)        // 16 chunks
#define KPW  (KC / NW)          // 16 k per wave per chunk
#define NG   (KPW / 2)          // 8 groups of 2 k
#define SSTR 36                 // tree-reduce lane stride (floats)
#define TSTR 68                 // logit tile row stride (floats)

typedef float f2 __attribute__((ext_vector_type(2)));
typedef float f4 __attribute__((ext_vector_type(4)));

// Block: 32 rows x 64 experts. x staged in LDS (coalesced f4 writes,
// XOR-swizzled by rs=row>>2 so the 8 concurrent row-groups of a read hit
// distinct banks). w loaded per-lane (f4 pairs, L2-resident), depth-2
// prefetch in two statically-indexed buffers. Lane = (rs = lane>>3: rows
// rs*4..+3) x (es = lane&7: experts es*8..+7); acc = f2[4][4] = 32 floats
// -> v_pk_fma_f32. K split 8 ways across waves; LDS tree reduce; wave-0
// epilogue (32 rows, lanes 0-31).
__global__ __launch_bounds__(BLOCK, 4) void gate_main(
    const float* __restrict__ x, const float* __restrict__ gw,
    const float* __restrict__ gb, float* __restrict__ out_w,
    float* __restrict__ out_idx, float* __restrict__ ws)
{
    // union: stage[32][128] (4096 f, 16 KB) / 2 tree slots (2*2304 f);
    // logit tile (32*68 f) lives inside slot region after tree is done.
    __shared__ float smem[4800];
    float* red  = smem;
    float* meta = smem + 4608;        // 32 * {i1,i2,w1,w2}
    float* scnt = smem + 4736;        // 64 selection counts

    const int tid   = threadIdx.x;
    const int lane  = tid & 63;
    const int wid   = __builtin_amdgcn_readfirstlane(tid >> 6);
    const int es    = lane & 7;       // experts es*8 .. es*8+7
    const int rs    = lane >> 3;      // rows rs*4 .. rs*4+3
    const int rbase = blockIdx.x * ROWS;

    // ---- staging geometry: thread t -> row t>>4, f4 slots (t&15), +16 ----
    const int srow = tid >> 4;                    // 0..31
    const int sgz  = (srow >> 2) & 7;             // swizzle group = rs of row
    const int ss   = tid & 15;
    const float* sgp = x + (size_t)(rbase + srow) * KDIM + ss * 4;
    float* sd0 = smem + srow * 128 + ((ss ^ sgz) * 4);
    float* sd1 = smem + srow * 128 + (((ss + 16) ^ sgz) * 4);

    f2 a[4][4];                       // a[i][j] = row rs*4+i, exp es*8+2j..+1
#pragma unroll
    for (int i = 0; i < 4; ++i)
#pragma unroll
        for (int j = 0; j < 4; ++j) a[i][j] = (f2){0.f, 0.f};

    // ---- stage chunk 0, keep chunk 1 in registers ----
    f4 s0 = *(const f4*)(sgp);
    f4 s1 = *(const f4*)(sgp + 64);
    *(f4*)sd0 = s0;
    *(f4*)sd1 = s1;
    s0 = *(const f4*)(sgp + KC);
    s1 = *(const f4*)(sgp + KC + 64);
    __syncthreads();

    // ---- w prefetch depth-2: buffer A = even group, B = odd group ----
    // group G = c*NG + g; first k of group = (G>>3)*KC + wid*KPW + (G&7)*2
    const float* wp = gw + es * 8;
#define LDW(D0, D1, D2, D3, kf)                                   \
    do {                                                          \
        const float* _w = wp + (size_t)(kf) * NEXP;               \
        D0 = *(const f4*)(_w);      D1 = *(const f4*)(_w + 4);    \
        D2 = *(const f4*)(_w + 64); D3 = *(const f4*)(_w + 68);   \
    } while (0)

    f4 A0, A1, A2, A3, B0, B1, B2, B3;
    LDW(A0, A1, A2, A3, wid * KPW);          // G = 0
    LDW(B0, B1, B2, B3, wid * KPW + 2);      // G = 1

    for (int c = 0; c < NCH; ++c) {
#pragma unroll
        for (int g = 0; g < NG; g += 2) {
            // ===== group g (buffer A) =====
            {
                const int kk = wid * KPW + g * 2;   // chunk-local float k
                f2 xr[4];
#pragma unroll
                for (int i = 0; i < 4; ++i)
                    xr[i] = *(const f2*)(smem + (rs * 4 + i) * 128 +
                                         (kk ^ (rs * 4)));
#pragma unroll
                for (int t = 0; t < 2; ++t) {
                    const f4 wlo = t ? A2 : A0;
                    const f4 whi = t ? A3 : A1;
                    const f2 w0 = {wlo[0], wlo[1]};
                    const f2 w1 = {wlo[2], wlo[3]};
                    const f2 w2 = {whi[0], whi[1]};
                    const f2 w3 = {whi[2], whi[3]};
#pragma unroll
                    for (int i = 0; i < 4; ++i) {
                        const f2 xv = {xr[i][t], xr[i][t]};
                        a[i][0] = __builtin_elementwise_fma(xv, w0, a[i][0]);
                        a[i][1] = __builtin_elementwise_fma(xv, w1, a[i][1]);
                        a[i][2] = __builtin_elementwise_fma(xv, w2, a[i][2]);
                        a[i][3] = __builtin_elementwise_fma(xv, w3, a[i][3]);
                    }
                }
                const int Gn = c * NG + g + 2;      // next even group
                const int kn = (Gn < NCH * NG)
                             ? (Gn >> 3) * KC + wid * KPW + (Gn & 7) * 2 : 0;
                LDW(A0, A1, A2, A3, kn);
            }
            // ===== group g+1 (buffer B) =====
            {
                const int kk = wid * KPW + g * 2 + 2;
                f2 xr[4];
#pragma unroll
                for (int i = 0; i < 4; ++i)
                    xr[i] = *(const f2*)(smem + (rs * 4 + i) * 128 +
                                         (kk ^ (rs * 4)));
#pragma unroll
                for (int t = 0; t < 2; ++t) {
                    const f4 wlo = t ? B2 : B0;
                    const f4 whi = t ? B3 : B1;
                    const f2 w0 = {wlo[0], wlo[1]};
                    const f2 w1 = {wlo[2], wlo[3]};
                    const f2 w2 = {whi[0], whi[1]};
                    const f2 w3 = {whi[2], whi[3]};
#pragma unroll
                    for (int i = 0; i < 4; ++i) {
                        const f2 xv = {xr[i][t], xr[i][t]};
                        a[i][0] = __builtin_elementwise_fma(xv, w0, a[i][0]);
                        a[i][1] = __builtin_elementwise_fma(xv, w1, a[i][1]);
                        a[i][2] = __builtin_elementwise_fma(xv, w2, a[i][2]);
                        a[i][3] = __builtin_elementwise_fma(xv, w3, a[i][3]);
                    }
                }
                const int Gn = c * NG + g + 3;      // next odd group
                const int kn = (Gn < NCH * NG)
                             ? (Gn >> 3) * KC + wid * KPW + (Gn & 7) * 2 : 0;
                LDW(B0, B1, B2, B3, kn);
            }
        }
        __syncthreads();                 // all waves done reading chunk c
        if (c + 1 < NCH) {
            *(f4*)sd0 = s0;              // publish chunk c+1
            *(f4*)sd1 = s1;
            if (c + 2 < NCH) {           // chunk c+2 in flight during c+1
                s0 = *(const f4*)(sgp + (size_t)(c + 2) * KC);
                s1 = *(const f4*)(sgp + (size_t)(c + 2) * KC + 64);
            }
        }
        __syncthreads();                 // chunk c+1 visible
    }

    // ---- pairwise tree reduce of 8 k-partials via 2 LDS slots ----
    // flat f4 #q (q=0..7) = { a[q>>1][(q&1)*2], a[q>>1][(q&1)*2+1] }
    for (int half = NW / 2; half >= 1; half >>= 1) {
        for (int sub = 0; sub < half; sub += 2) {
            const int nslot = (half - sub < 2) ? (half - sub) : 2;
            __syncthreads();
            if (wid >= half + sub && wid < half + sub + nslot) {
                float* dst = red + (size_t)(wid - half - sub) * 64 * SSTR
                           + lane * SSTR;
#pragma unroll
                for (int q = 0; q < 8; ++q) {
                    f4 v = {a[q >> 1][(q & 1) * 2][0], a[q >> 1][(q & 1) * 2][1],
                            a[q >> 1][(q & 1) * 2 + 1][0], a[q >> 1][(q & 1) * 2 + 1][1]};
                    *(f4*)(dst + q * 4) = v;
                }
            }
            __syncthreads();
            if (wid >= sub && wid < sub + nslot) {
                const float* src = red + (size_t)(wid - sub) * 64 * SSTR
                                 + lane * SSTR;
#pragma unroll
                for (int q = 0; q < 8; ++q) {
                    f4 v = *(const f4*)(src + q * 4);
                    a[q >> 1][(q & 1) * 2][0]     += v.x;
                    a[q >> 1][(q & 1) * 2][1]     += v.y;
                    a[q >> 1][(q & 1) * 2 + 1][0] += v.z;
                    a[q >> 1][(q & 1) * 2 + 1][1] += v.w;
                }
            }
        }
    }

    // ---- wave 0: transpose outer-product layout -> row-major tile ----
    __syncthreads();
    if (wid == 0) {
#pragma unroll
        for (int i = 0; i < 4; ++i)
#pragma unroll
            for (int j = 0; j < 4; ++j)
                *(f2*)(red + (size_t)(rs * 4 + i) * TSTR + es * 8 + 2 * j) = a[i][j];
    }
    __syncthreads();

    // ---- epilogue: wave 0, lanes 0..31, lane = row ----
    int i1 = 0, i2 = 0;
    if (wid == 0) {
        scnt[lane] = 0.f;                // all 64 lanes zero the counts
        if (lane < ROWS) {
            float lg[64];
#pragma unroll
            for (int q = 0; q < 16; ++q) {
                f4 v = *(const f4*)(red + (size_t)lane * TSTR + q * 4);
                lg[q * 4 + 0] = v.x; lg[q * 4 + 1] = v.y;
                lg[q * 4 + 2] = v.z; lg[q * 4 + 3] = v.w;
            }
#pragma unroll
            for (int e = 0; e < NEXP; ++e) lg[e] += gb[e];

            // top-1 / top-2; strict > keeps lowest index on ties (lax.top_k)
            float v1 = lg[0];
#pragma unroll
            for (int e = 1; e < NEXP; ++e)
                if (lg[e] > v1) { v1 = lg[e]; i1 = e; }
            float v2 = -INFINITY;
#pragma unroll
            for (int e = 0; e < NEXP; ++e)
                if (e != i1 && lg[e] > v2) { v2 = lg[e]; i2 = e; }

            // full softmax (aux loss): probs overwrite this row of the tile
            float ssum = 0.f;
#pragma unroll
            for (int e = 0; e < NEXP; ++e) ssum += __expf(lg[e] - v1);
            const float sinv = 1.f / ssum;
            float* pr = red + (size_t)lane * TSTR;
#pragma unroll
            for (int e = 0; e < NEXP; ++e) pr[e] = __expf(lg[e] - v1) * sinv;

            // renormalized top-2 softmax weights
            const float e2 = __expf(v2 - v1);
            const float wa = 1.f / (1.f + e2);
            f4 m = {(float)i1, (float)i2, wa, e2 * wa};
            ((f4*)meta)[lane] = m;

            *(float2*)(out_idx + (size_t)(rbase + lane) * 2) =
                make_float2((float)i1, (float)i2);

            atomicAdd(&scnt[i1], 1.f);   // wave-ordered after the zeroing
            atomicAdd(&scnt[i2], 1.f);
        }
    }
    __syncthreads();
    if (wid == 0) {
        // per-expert prob column-sum over this block's 32 rows (lane=expert)
        float ps = 0.f;
#pragma unroll
        for (int r = 0; r < ROWS; ++r) ps += red[(size_t)r * TSTR + lane];
        atomicAdd(&ws[lane], ps);
        atomicAdd(&ws[NEXP + lane], scnt[lane]);
    }
    __syncthreads();

    // ---- gate-weight store: each wave writes 4 rows, coalesced ----
#pragma unroll
    for (int rr = 0; rr < 4; ++rr) {
        const int r = wid * 4 + rr;
        const f4 m = ((const f4*)meta)[r];       // broadcast read
        const float val = (lane == (int)m.x) ? m.z
                        : ((lane == (int)m.y) ? m.w : 0.f);
        out_w[((size_t)rbase + r) * NEXP + lane] = val;
    }
}

__global__ void gate_aux(const float* __restrict__ ws, float* __restrict__ out_aux)
{
    const int e = threadIdx.x;  // 64 threads
    const float frac = ws[NEXP + e] * (1.f / (float)(NTOK * 2));
    const float mp   = ws[e] * (1.f / (float)NTOK);
    float v = frac * mp * (float)NEXP;
#pragma unroll
    for (int off = 32; off; off >>= 1) v += __shfl_xor(v, off);
    if (e == 0) out_aux[0] = v;
}

extern "C" void kernel_launch(void* const* d_in, const int* in_sizes, int n_in,
                              void* d_out, int out_size, void* d_ws, size_t ws_size,
                              hipStream_t stream) {
    const float* x  = (const float*)d_in[0];
    const float* gw = (const float*)d_in[1];
    const float* gb = (const float*)d_in[2];

    float* out     = (float*)d_out;
    float* out_w   = out;                         // [16384*64]
    float* out_idx = out + (size_t)NTOK * NEXP;   // [16384*2] as floats
    float* out_aux = out_idx + (size_t)NTOK * 2;  // [1]
    float* ws      = (float*)d_ws;                // [128] floats

    (void)hipMemsetAsync(ws, 0, 2 * NEXP * sizeof(float), stream);
    gate_main<<<NTOK / ROWS, BLOCK, 0, stream>>>(x, gw, gb, out_w, out_idx, ws);
    gate_aux<<<1, 64, 0, stream>>>(ws, out_aux);
}

// Round 11
// 124.260 us; speedup vs baseline: 10.4382x; 10.4382x over previous
//
#include <hip/hip_runtime.h>
#include <math.h>

#define NTOK 16384
#define KDIM 2048
#define NEXP 64
#define NW   16
#define BLOCK (NW * 64)          // 1024 threads, 16 waves
#define RPAD 68                  // padded row stride for reduce buffer
#define PSZ  ((size_t)NTOK * NEXP)

typedef float f4 __attribute__((ext_vector_type(4)));
typedef float f16s __attribute__((ext_vector_type(16)));

// Wave-uniform w row (256 B) via the scalar pipe. Early-clobber ("=&s") is
// REQUIRED: outputs are written by the first s_load while the address input
// is still live for the remaining three — without "&" the allocator may
// overlap them (round-10 fault, round-4 corruption).
#define LOAD_W_ROW(wA, wB, wC, wD, wk)                                  \
    do {                                                                \
        asm volatile("s_load_dwordx16 %0, %4, 0x0\n\t"                  \
                     "s_load_dwordx16 %1, %4, 0x40\n\t"                 \
                     "s_load_dwordx16 %2, %4, 0x80\n\t"                 \
                     "s_load_dwordx16 %3, %4, 0xc0"                     \
                     : "=&s"(wA), "=&s"(wB), "=&s"(wC), "=&s"(wD)       \
                     : "s"(wk));                                        \
        asm volatile("s_waitcnt lgkmcnt(0)"                             \
                     : "+s"(wA), "+s"(wB), "+s"(wC), "+s"(wD));         \
    } while (0)

// ---------------- kernel 1: split-K(x2) partial GEMM ----------------
// grid 512: rg = bid>>1 (64 rows), kq = bid&1 (k half). lane = row,
// scalar-path w, immediate lgkmcnt(0) (proven round-3 body, KS=64).
// 2 blocks/CU -> 8 waves/SIMD: SMEM latency overlaps across blocks.
__global__ __launch_bounds__(BLOCK, 4) void gate_gemm(
    const float* __restrict__ x, const float* __restrict__ gw,
    float* __restrict__ p0, float* __restrict__ p1)
{
    __shared__ float red[2 * 64 * RPAD];

    const int tid  = threadIdx.x;
    const int lane = tid & 63;
    const int wid  = __builtin_amdgcn_readfirstlane(tid >> 6);
    const int rg   = blockIdx.x >> 1;
    const int kq   = blockIdx.x & 1;
    const int row  = rg * 64 + lane;            // lane = row
    const int KS   = 64;                        // k per wave
    const int k0   = kq * (KDIM / 2) + wid * KS;

    const float* xrow  = x  + (size_t)row * KDIM + k0;
    const float* wbase = gw + (size_t)k0 * NEXP;

    float acc[NEXP];
#pragma unroll
    for (int e = 0; e < NEXP; ++e) acc[e] = 0.f;

    f4 xa = *(const f4*)(xrow);
    f4 xb = *(const f4*)(xrow + 4);
    for (int c = 0; c < KS / 8; ++c) {          // 8 chunks of 8 k
        const int cn = (c + 1 < KS / 8) ? (c + 1) : c;
        f4 na = *(const f4*)(xrow + cn * 8);
        f4 nb = *(const f4*)(xrow + cn * 8 + 4);
        const float xs[8] = {xa[0], xa[1], xa[2], xa[3],
                             xb[0], xb[1], xb[2], xb[3]};
#pragma unroll
        for (int j = 0; j < 8; ++j) {
            const float* wk = wbase + (size_t)(c * 8 + j) * NEXP;
            f16s wA, wB, wC, wD;
            LOAD_W_ROW(wA, wB, wC, wD, wk);
#pragma unroll
            for (int t = 0; t < 16; ++t) acc[t]      = fmaf(xs[j], wA[t], acc[t]);
#pragma unroll
            for (int t = 0; t < 16; ++t) acc[16 + t] = fmaf(xs[j], wB[t], acc[16 + t]);
#pragma unroll
            for (int t = 0; t < 16; ++t) acc[32 + t] = fmaf(xs[j], wC[t], acc[32 + t]);
#pragma unroll
            for (int t = 0; t < 16; ++t) acc[48 + t] = fmaf(xs[j], wD[t], acc[48 + t]);
        }
        xa = na; xb = nb;
    }

    // ---- pairwise tree reduce of 16 k-partials via 2 LDS slots ----
    for (int half = NW / 2; half >= 1; half >>= 1) {
        for (int sub = 0; sub < half; sub += 2) {
            const int nslot = (half - sub < 2) ? (half - sub) : 2;
            __syncthreads();
            if (wid >= half + sub && wid < half + sub + nslot) {
                float* dst = red + (size_t)(wid - half - sub) * 64 * RPAD + lane * RPAD;
#pragma unroll
                for (int q = 0; q < 16; ++q) {
                    f4 v = {acc[q*4+0], acc[q*4+1], acc[q*4+2], acc[q*4+3]};
                    *(f4*)(dst + q * 4) = v;
                }
            }
            __syncthreads();
            if (wid >= sub && wid < sub + nslot) {
                const float* src = red + (size_t)(wid - sub) * 64 * RPAD + lane * RPAD;
#pragma unroll
                for (int q = 0; q < 16; ++q) {
                    f4 v = *(const f4*)(src + q * 4);
                    acc[q*4+0] += v.x; acc[q*4+1] += v.y;
                    acc[q*4+2] += v.z; acc[q*4+3] += v.w;
                }
            }
        }
    }

    // ---- wave 0: acc -> LDS slot 0; all waves store coalesced ----
    __syncthreads();
    if (wid == 0) {
#pragma unroll
        for (int q = 0; q < 16; ++q) {
            f4 v = {acc[q*4+0], acc[q*4+1], acc[q*4+2], acc[q*4+3]};
            *(f4*)(red + (size_t)lane * RPAD + q * 4) = v;
        }
    }
    __syncthreads();
    float* dst = (kq == 0 ? p0 : p1) + (size_t)rg * 64 * NEXP;
    ((f4*)dst)[tid] = *(const f4*)(red + (size_t)(tid >> 4) * RPAD + (tid & 15) * 4);
}

// ---------------- kernel 2: combine + top-2 + softmax + aux partials ----------------
#define W2 16
__global__ __launch_bounds__(1024) void gate_finish(
    const float* __restrict__ p0, const float* __restrict__ p1,
    const float* __restrict__ gb, float* __restrict__ out_w,
    float* __restrict__ out_idx, float* __restrict__ aux)
{
    __shared__ float red[2 * W2 * NEXP];
    const int tid  = threadIdx.x;
    const int lane = tid & 63;
    const int wid  = tid >> 6;

    float psum = 0.f, cnt = 0.f;
#pragma unroll
    for (int rr = 0; rr < 4; ++rr) {
        const size_t row = (size_t)blockIdx.x * 64 + wid * 4 + rr;
        const size_t o   = row * NEXP + lane;
        const float l = p0[o] + p1[o] + gb[lane];

        // top-1 / top-2 butterfly; ties -> lower index (matches lax.top_k)
        float v1 = l; int i1 = lane;
#pragma unroll
        for (int off = 32; off; off >>= 1) {
            const float ov = __shfl_xor(v1, off);
            const int   oi = __shfl_xor(i1, off);
            if (ov > v1 || (ov == v1 && oi < i1)) { v1 = ov; i1 = oi; }
        }
        float v2 = (lane == i1) ? -INFINITY : l; int i2 = lane;
#pragma unroll
        for (int off = 32; off; off >>= 1) {
            const float ov = __shfl_xor(v2, off);
            const int   oi = __shfl_xor(i2, off);
            if (ov > v2 || (ov == v2 && oi < i2)) { v2 = ov; i2 = oi; }
        }

        const float p = __expf(l - v1);
        float s = p;
#pragma unroll
        for (int off = 32; off; off >>= 1) s += __shfl_xor(s, off);
        psum += p / s;
        cnt  += ((lane == i1) ? 1.f : 0.f) + ((lane == i2) ? 1.f : 0.f);

        const float e2 = __expf(v2 - v1);
        const float wa = 1.f / (1.f + e2);
        out_w[o] = (lane == i1) ? wa : ((lane == i2) ? e2 * wa : 0.f);
        if (lane == 0)
            *(float2*)(out_idx + row * 2) = make_float2((float)i1, (float)i2);
    }

    red[wid * NEXP + lane]             = psum;
    red[W2 * NEXP + wid * NEXP + lane] = cnt;
    __syncthreads();
    if (tid < 2 * NEXP) {
        const int half = tid >> 6, e = tid & 63;
        float v = 0.f;
#pragma unroll
        for (int w = 0; w < W2; ++w) v += red[half * W2 * NEXP + w * NEXP + e];
        atomicAdd(&aux[half * NEXP + e], v);   // 256 adds per address total
    }
}

// ---------------- kernel 3: aux loss scalar ----------------
__global__ void gate_aux(const float* __restrict__ aux, float* __restrict__ out_aux)
{
    const int e = threadIdx.x;  // 64 threads
    const float frac = aux[NEXP + e] * (1.f / (float)(NTOK * 2));
    const float mp   = aux[e] * (1.f / (float)NTOK);
    float v = frac * mp * (float)NEXP;
#pragma unroll
    for (int off = 32; off; off >>= 1) v += __shfl_xor(v, off);
    if (e == 0) out_aux[0] = v;
}

// ---------------- fallback: round-3 monolith (small ws) ----------------
#define MKS (KDIM / NW)          // 128 k per wave
__global__ __launch_bounds__(BLOCK, 4) void gate_mono(
    const float* __restrict__ x, const float* __restrict__ gw,
    const float* __restrict__ gb, float* __restrict__ out_w,
    float* __restrict__ out_idx, float* __restrict__ ws)
{
    __shared__ float red[2 * 64 * RPAD];
    __shared__ float meta[64 * 4];
    __shared__ float scnt[NEXP];

    const int tid  = threadIdx.x;
    const int lane = tid & 63;
    const int wid  = __builtin_amdgcn_readfirstlane(tid >> 6);
    const int row  = blockIdx.x * 64 + lane;

    const float* xrow  = x  + (size_t)row * KDIM + wid * MKS;
    const float* wbase = gw + (size_t)wid * MKS * NEXP;

    float acc[NEXP];
#pragma unroll
    for (int e = 0; e < NEXP; ++e) acc[e] = 0.f;

    f4 xa = *(const f4*)(xrow);
    f4 xb = *(const f4*)(xrow + 4);
    for (int c = 0; c < MKS / 8; ++c) {
        const int cn = (c + 1 < MKS / 8) ? (c + 1) : c;
        f4 na = *(const f4*)(xrow + cn * 8);
        f4 nb = *(const f4*)(xrow + cn * 8 + 4);
        const float xs[8] = {xa[0], xa[1], xa[2], xa[3],
                             xb[0], xb[1], xb[2], xb[3]};
#pragma unroll
        for (int j = 0; j < 8; ++j) {
            const float* wk = wbase + (size_t)(c * 8 + j) * NEXP;
            f16s wA, wB, wC, wD;
            LOAD_W_ROW(wA, wB, wC, wD, wk);
#pragma unroll
            for (int t = 0; t < 16; ++t) acc[t]      = fmaf(xs[j], wA[t], acc[t]);
#pragma unroll
            for (int t = 0; t < 16; ++t) acc[16 + t] = fmaf(xs[j], wB[t], acc[16 + t]);
#pragma unroll
            for (int t = 0; t < 16; ++t) acc[32 + t] = fmaf(xs[j], wC[t], acc[32 + t]);
#pragma unroll
            for (int t = 0; t < 16; ++t) acc[48 + t] = fmaf(xs[j], wD[t], acc[48 + t]);
        }
        xa = na; xb = nb;
    }

    for (int half = NW / 2; half >= 1; half >>= 1) {
        for (int sub = 0; sub < half; sub += 2) {
            const int nslot = (half - sub < 2) ? (half - sub) : 2;
            __syncthreads();
            if (wid >= half + sub && wid < half + sub + nslot) {
                float* dst = red + (size_t)(wid - half - sub) * 64 * RPAD + lane * RPAD;
#pragma unroll
                for (int q = 0; q < 16; ++q) {
                    f4 v = {acc[q*4+0], acc[q*4+1], acc[q*4+2], acc[q*4+3]};
                    *(f4*)(dst + q * 4) = v;
                }
            }
            __syncthreads();
            if (wid >= sub && wid < sub + nslot) {
                const float* src = red + (size_t)(wid - sub) * 64 * RPAD + lane * RPAD;
#pragma unroll
                for (int q = 0; q < 16; ++q) {
                    f4 v = *(const f4*)(src + q * 4);
                    acc[q*4+0] += v.x; acc[q*4+1] += v.y;
                    acc[q*4+2] += v.z; acc[q*4+3] += v.w;
                }
            }
        }
    }

    __syncthreads();
    int i1 = 0, i2 = 0;
    if (wid == 0) {
#pragma unroll
        for (int e = 0; e < NEXP; ++e) acc[e] += gb[e];
        float v1 = acc[0];
#pragma unroll
        for (int e = 1; e < NEXP; ++e)
            if (acc[e] > v1) { v1 = acc[e]; i1 = e; }
        float v2 = -INFINITY;
#pragma unroll
        for (int e = 0; e < NEXP; ++e)
            if (e != i1 && acc[e] > v2) { v2 = acc[e]; i2 = e; }
        float ssum = 0.f;
#pragma unroll
        for (int e = 0; e < NEXP; ++e) ssum += __expf(acc[e] - v1);
        const float sinv = 1.f / ssum;
        float* pr = red + (size_t)lane * RPAD;
#pragma unroll
        for (int e = 0; e < NEXP; ++e) pr[e] = __expf(acc[e] - v1) * sinv;
        const float e2 = __expf(v2 - v1);
        const float w1 = 1.f / (1.f + e2);
        f4 m = {(float)i1, (float)i2, w1, e2 * w1};
        ((f4*)meta)[lane] = m;
        *(float2*)(out_idx + (size_t)row * 2) = make_float2((float)i1, (float)i2);
        scnt[lane] = 0.f;
        atomicAdd(&scnt[i1], 1.f);
        atomicAdd(&scnt[i2], 1.f);
    }
    __syncthreads();
    if (wid == 0) {
        float ps = 0.f;
#pragma unroll
        for (int r = 0; r < 64; ++r) ps += red[(size_t)r * RPAD + lane];
        atomicAdd(&ws[lane], ps);
        atomicAdd(&ws[NEXP + lane], scnt[lane]);
    }
    __syncthreads();
#pragma unroll
    for (int rr = 0; rr < 4; ++rr) {
        const int r = wid * 4 + rr;
        const f4 m = ((const f4*)meta)[r];
        const float val = (lane == (int)m.x) ? m.z
                        : ((lane == (int)m.y) ? m.w : 0.f);
        out_w[((size_t)blockIdx.x * 64 + r) * NEXP + lane] = val;
    }
}

extern "C" void kernel_launch(void* const* d_in, const int* in_sizes, int n_in,
                              void* d_out, int out_size, void* d_ws, size_t ws_size,
                              hipStream_t stream) {
    const float* x  = (const float*)d_in[0];
    const float* gw = (const float*)d_in[1];
    const float* gb = (const float*)d_in[2];

    float* out     = (float*)d_out;
    float* out_w   = out;                         // [16384*64]
    float* out_idx = out + (size_t)NTOK * NEXP;   // [16384*2] as floats
    float* out_aux = out_idx + (size_t)NTOK * 2;  // [1]
    float* ws      = (float*)d_ws;

    const size_t need = (2 * PSZ + 2 * NEXP) * sizeof(float);
    if (ws_size >= need) {
        float* p0  = ws;
        float* p1  = ws + PSZ;
        float* aux = ws + 2 * PSZ;
        (void)hipMemsetAsync(aux, 0, 2 * NEXP * sizeof(float), stream);
        gate_gemm<<<(NTOK / 64) * 2, BLOCK, 0, stream>>>(x, gw, p0, p1);
        gate_finish<<<NTOK / 64, 1024, 0, stream>>>(p0, p1, gb, out_w, out_idx, aux);
        gate_aux<<<1, 64, 0, stream>>>(aux, out_aux);
    } else {
        (void)hipMemsetAsync(ws, 0, 2 * NEXP * sizeof(float), stream);
        gate_mono<<<NTOK / 64, BLOCK, 0, stream>>>(x, gw, gb, out_w, out_idx, ws);
        gate_aux<<<1, 64, 0, stream>>>(ws, out_aux);
    }
}